// Round 3
// baseline (204.508 us; speedup 1.0000x reference)
//
#include <hip/hip_runtime.h>
#include <hip/hip_cooperative_groups.h>
#include <math.h>

namespace cg = cooperative_groups;

// RC thermal model: x' = A x + b0*To(t) + Bq, RK4 h=30, T=1e6 steps.
// Per step: x_{t+1} = M x_t + c + al*To[t] + be*To[t+1].
// R11: fuse K1(block_agg)+K2(scan_expand) into ONE cooperative kernel.
// R9 counters showed latency-bound (occ 15%, VALU 17%, HBM 20%): halving
// scan work (CH 4->8) was time-neutral, so the win is removing the
// DUPLICATED fold+scan pass and a launch gap. CH=8 grid = 489 blocks
// <= coop capacity 512 at (256,2) -- this is what R9's CH=8 bought us.
// Structure: setup (plain launch) + fused coop kernel:
//   phase A: fold + wave shfl-scan (once) -> se (exclusive), Tw; LDS tree
//            -> agg[b]; __threadfence; grid.sync()
//   phase B: truncated 32-block lookback + merged prefix
//            x = M^(8j)(M^(512w)Xstart + P_w) + se + 8-step expand.
// All per-thread arrays constant-indexed / fully unrolled (no scratch).

#define S_STEPS 999999
#define CH      8
#define BLK     256
#define NB      489          // 489*256*8 = 1,001,472 >= S_STEPS
#define NCHUNK  125000       // active chunks (last partial: 7 steps)
#define LASTFULL 124998      // g <= LASTFULL: To[8g+8] in bounds

// ws float offsets (16B-aligned)
#define OFF_M   0            // 144: M
#define OFF_C   144          // 12
#define OFF_AL  156          // 12
#define OFF_BE  168          // 12
#define OFF_K   192          // 120: K cols [col][12], col0 = const (10 cols)
#define OFF_P2  320          // 8*144: [l]=M^(8*2^l) l=0..5 (M^8..M^256),
                             //        [6]=M^512, [7]=M^1024
#define OFF_PA  1472         // 144: M^1536
#define OFF_PL  1616         // 3*144: M^2048, M^4096, M^6144
#define OFF_PD  2048         // 8*144: Pd[i]=M^(8192*i), i=0..7 (Pd[0]=I)
#define OFF_AGG 3200         // 489*12 block aggregates (end 9068 ~ 36 KB)

#define FMA4(Q,a,b,c,d,acc) fmaf((Q).w,(d),fmaf((Q).z,(c),fmaf((Q).y,(b),fmaf((Q).x,(a),(acc)))))

// y += P(12x12 row-major, 16B-aligned) * x
__device__ __forceinline__ void mv_acc(const float* Pf, const float* x, float* y) {
  const float4* P = reinterpret_cast<const float4*>(Pf);
#pragma unroll
  for (int i = 0; i < 12; ++i) {
    float4 a = P[3*i], b = P[3*i+1], c = P[3*i+2];
    y[i] = FMA4(c, x[8],x[9],x[10],x[11],
            FMA4(b, x[4],x[5],x[6],x[7],
             FMA4(a, x[0],x[1],x[2],x[3], y[i])));
  }
}

// dot(P row (16B-aligned), xv[0..11] scalars)
__device__ __forceinline__ float rowdot(const float* Prow, const float* xv) {
  const float4* P = reinterpret_cast<const float4*>(Prow);
  float4 a = P[0], b = P[1], c = P[2];
  return FMA4(c, xv[8],xv[9],xv[10],xv[11],
          FMA4(b, xv[4],xv[5],xv[6],xv[7],
           FMA4(a, xv[0],xv[1],xv[2],xv[3], 0.f)));
}

// v = K[:,0] + sum_{s=0..8} K[:,s+1]*tos[s]
__device__ __forceinline__ void fold_chunk(const float* __restrict__ cons,
                                           const float* tos, float* v) {
  const float4* Kq = reinterpret_cast<const float4*>(cons + OFF_K);
  float4 c0=Kq[0], c1=Kq[1], c2=Kq[2];
  v[0]=c0.x; v[1]=c0.y; v[2]=c0.z; v[3]=c0.w;
  v[4]=c1.x; v[5]=c1.y; v[6]=c1.z; v[7]=c1.w;
  v[8]=c2.x; v[9]=c2.y; v[10]=c2.z; v[11]=c2.w;
#pragma unroll
  for (int s = 0; s < 9; ++s) {
    float ts = tos[s];
    float4 ka=Kq[3*(s+1)], kb=Kq[3*(s+1)+1], kc=Kq[3*(s+1)+2];
    v[0]=fmaf(ka.x,ts,v[0]); v[1]=fmaf(ka.y,ts,v[1]); v[2]=fmaf(ka.z,ts,v[2]); v[3]=fmaf(ka.w,ts,v[3]);
    v[4]=fmaf(kb.x,ts,v[4]); v[5]=fmaf(kb.y,ts,v[5]); v[6]=fmaf(kb.z,ts,v[6]); v[7]=fmaf(kb.w,ts,v[7]);
    v[8]=fmaf(kc.x,ts,v[8]); v[9]=fmaf(kc.y,ts,v[9]); v[10]=fmaf(kc.z,ts,v[10]); v[11]=fmaf(kc.w,ts,v[11]);
  }
}

__global__ void __launch_bounds__(512) setup_kernel(
    const float* __restrict__ t_eval, const float* __restrict__ A,
    const float* __restrict__ Bm, const float* __restrict__ loads_raw,
    const float* __restrict__ areas, float* ws) {
  __shared__ double H1[144], H2[144], H3[144], H4[144], Md[144];
  __shared__ double Qa[144], Qb[144];
  __shared__ double C512s[144], C1024s[144], C2048s[144], C4096s[144];
  __shared__ double C8192s[144], C16384s[144], C32768s[144], Pd3s[144];
  __shared__ double cd[12], ald[12], bed[12], b0d[12], bqd[12];
  __shared__ double Vv[3][12], Kd[120];
  int t = threadIdx.x;
  double h = (double)t_eval[1] - (double)t_eval[0];
  if (t < 144) H1[t] = h * (double)A[t];
  if (t < 12) {
    b0d[t] = (double)Bm[t*11];
    double s = 0.0;
    for (int r = 0; r < 10; ++r) {
      double gq = 50.0 / (1.0 + exp(-(double)loads_raw[10 + r]));
      s += (double)Bm[t*11 + 1 + r] * (gq * (double)areas[r]);
    }
    bqd[t] = s;
  }
  if (t < 120) Kd[t] = 0.0;
  __syncthreads();
  if (t < 144) {                              // H2 = H1*H1
    int i=t/12, j=t%12; double s=0.0;
#pragma unroll
    for (int m = 0; m < 12; ++m) s += H1[i*12+m]*H1[m*12+j];
    H2[t]=s;
  }
  __syncthreads();
  if (t < 288) {                              // H3 = H2*H1 | H4 = H2*H2
    int w=t/144, e=t%144, i=e/12, j=e%12;
    const double* Bp = w ? H2 : H1;
    double s = 0.0;
#pragma unroll
    for (int m = 0; m < 12; ++m) s += H2[i*12+m]*Bp[m*12+j];
    (w ? H4 : H3)[e] = s;
  }
  __syncthreads();
  if (t < 12) {
    double hb=0,h2b=0,h3b=0,hb0=0,h2b0=0,h3b0=0;
#pragma unroll
    for (int m = 0; m < 12; ++m) {
      hb  += H1[t*12+m]*bqd[m]; h2b  += H2[t*12+m]*bqd[m]; h3b  += H3[t*12+m]*bqd[m];
      hb0 += H1[t*12+m]*b0d[m]; h2b0 += H2[t*12+m]*b0d[m]; h3b0 += H3[t*12+m]*b0d[m];
    }
    double h6 = h / 6.0;
    cd[t]  = h6*(6.0*bqd[t] + 3.0*hb + h2b + 0.25*h3b);
    ald[t] = h6*(3.0*b0d[t] + 2.0*hb0 + 0.75*h2b0 + 0.25*h3b0);
    bed[t] = h6*(3.0*b0d[t] + hb0 + 0.25*h2b0);
    Vv[0][t]=ald[t]; Vv[1][t]=bed[t]; Vv[2][t]=cd[t];
    // r=0 K contributions (CH=8): col8 += al, col9 += be, col0 += c
    Kd[96+t] += ald[t]; Kd[108+t] += bed[t]; Kd[t] += cd[t];
  }
  if (t >= 144 && t < 288) {
    int e=t-144, i=e/12, j=e%12;
    Md[e] = (i==j ? 1.0 : 0.0) + H1[e] + 0.5*H2[e] + H3[e]/6.0 + H4[e]/24.0;
  }
  __syncthreads();
  if (t < 144) { ws[OFF_M+t] = (float)Md[t]; Qa[t] = Md[t]; }
  if (t < 12) {
    ws[OFF_C+t]=(float)cd[t]; ws[OFF_AL+t]=(float)ald[t]; ws[OFF_BE+t]=(float)bed[t];
  }
  __syncthreads();
  // chain r=1..15: src=M^(2^(r-1)) -> dst=M^(2^r). Overlapped K rounds
  // r=1..7 (threads 256..291): Vv=M^r*{al,be,c}; Kd cols (8-r),(9-r),0.
  double* src = Qa; double* dst = Qb;
  for (int r = 1; r <= 15; ++r) {
    double acc = 0.0, ks = 0.0;
    if (t < 144) {
      int i=t/12, j=t%12;
#pragma unroll
      for (int m = 0; m < 12; ++m) acc += src[i*12+m]*src[m*12+j];
    }
    int w=0, i2=0;
    if (r <= 7 && t >= 256 && t < 292) {
      w=(t-256)/12; i2=(t-256)%12;
#pragma unroll
      for (int m = 0; m < 12; ++m) ks += Md[i2*12+m]*Vv[w][m];
    }
    __syncthreads();
    if (t < 144) {
      dst[t] = acc;
      if (r >= 3 && r <= 10) ws[OFF_P2+(r-3)*144+t] = (float)acc;  // M^8..M^1024
      if (r == 9)  C512s[t]=acc;
      if (r == 10) C1024s[t]=acc;
      if (r == 11) { C2048s[t]=acc;  ws[OFF_PL+t]       = (float)acc; }
      if (r == 12) { C4096s[t]=acc;  ws[OFF_PL+144+t]   = (float)acc; }
      if (r == 13) { C8192s[t]=acc;  ws[OFF_PD+144+t]   = (float)acc; }  // Pd[1]
      if (r == 14) { C16384s[t]=acc; ws[OFF_PD+2*144+t] = (float)acc; }  // Pd[2]
      if (r == 15) { C32768s[t]=acc; ws[OFF_PD+4*144+t] = (float)acc; }  // Pd[4]
    }
    if (r <= 7 && t >= 256 && t < 292) {
      Vv[w][i2] = ks;
      if (w == 0) Kd[(8-r)*12+i2] += ks;
      else if (w == 1) Kd[(9-r)*12+i2] += ks;
      else Kd[i2] += ks;
    }
    __syncthreads();
    double* tmp = src; src = dst; dst = tmp;    // src = M^(2^r)
  }
  if (t < 120) ws[OFF_K+t] = (float)Kd[t];
  if (t < 144) ws[OFF_PD+t] = (t % 13 == 0) ? 1.f : 0.f;   // Pd[0]=I
  // product round A: M^1536=M^512*M^1024 ; M^6144=M^2048*M^4096 ;
  //                  Pd[3]=M^8192*M^16384
  if (t < 432) {
    int w=t/144, e=t%144, i=e/12, j=e%12;
    const double* Ap = (w==0) ? C512s  : ((w==1) ? C2048s : C8192s);
    const double* Bp = (w==0) ? C1024s : ((w==1) ? C4096s : C16384s);
    double s = 0.0;
#pragma unroll
    for (int m = 0; m < 12; ++m) s += Ap[i*12+m]*Bp[m*12+j];
    if (w==0) ws[OFF_PA+e] = (float)s;
    else if (w==1) ws[OFF_PL+2*144+e] = (float)s;
    else { ws[OFF_PD+3*144+e] = (float)s; Pd3s[e] = s; }
  }
  __syncthreads();
  // product round B: Pd[5]=Pd[1]*M^32768 ; Pd[6]=Pd[2]*M^32768 ;
  //                  Pd[7]=Pd[3]*M^32768
  if (t < 432) {
    int w=t/144, e=t%144, i=e/12, j=e%12;
    const double* Ap = (w==0) ? C8192s : ((w==1) ? C16384s : Pd3s);
    double s = 0.0;
#pragma unroll
    for (int m = 0; m < 12; ++m) s += Ap[i*12+m]*C32768s[m*12+j];
    ws[OFF_PD+(5+w)*144+e] = (float)s;
  }
}

// Fused K1+K2 (cooperative): fold+scan ONCE; block aggregate -> grid.sync
// -> truncated lookback + merged prefix + 8-step expand.
__global__ void __launch_bounds__(BLK, 2) fused_scan(
    const float* __restrict__ cons, const float* __restrict__ To,
    const float* __restrict__ x0, float* __restrict__ agg,
    float* __restrict__ out) {
  __shared__ __align__(16) float Tw[48];      // wave totals
  __shared__ __align__(16) float Ta[24];      // agg tree level 1
  __shared__ __align__(16) float Pw[48];      // wave exclusive prefixes
  __shared__ __align__(16) float lkb[32*12];  // lookback stage-1 partials
  __shared__ __align__(16) float yv[8*12];
  __shared__ __align__(16) float zv[8*12];
  __shared__ __align__(16) float Xs[12];
  __shared__ __align__(16) float Qw[48];      // M^(512w)*Xs + Pw
  cg::grid_group grid = cg::this_grid();
  int k = threadIdx.x, b = blockIdx.x;
  int g = b*BLK + k, base = g*CH;
  bool active = (g < NCHUNK), fullc = (g <= LASTFULL);
  float to_[9];
#pragma unroll
  for (int i = 0; i < 9; ++i) to_[i] = 0.f;
  if (active) {
    const float4* tp = reinterpret_cast<const float4*>(To + base);
    float4 ta = tp[0], tb = tp[1];
    to_[0]=ta.x; to_[1]=ta.y; to_[2]=ta.z; to_[3]=ta.w;
    to_[4]=tb.x; to_[5]=tb.y; to_[6]=tb.z; to_[7]=tb.w;
    to_[8] = fullc ? To[base+8] : 0.f;
  }
  float v[12];
  if (fullc) fold_chunk(cons, to_, v);
  else {
#pragma unroll
    for (int i = 0; i < 12; ++i) v[i] = 0.f;
  }
  if (g == 0) {                      // fold x0 into chunk 0: v += M^8 x0
    float xi[12];
#pragma unroll
    for (int i = 0; i < 12; ++i) xi[i] = x0[i];
    mv_acc(cons + OFF_P2, xi, v);
  }
  int j = k & 63, w = k >> 6;
#pragma unroll
  for (int l = 0; l < 6; ++l) {      // in-wave inclusive scan
    int off = 1 << l;
    float nb[12];
#pragma unroll
    for (int i = 0; i < 12; ++i) nb[i] = __shfl_up(v[i], (unsigned)off, 64);
    if (j >= off) mv_acc(cons + OFF_P2 + l*144, nb, v);
  }
  float se[12];                      // exclusive in-wave scan
#pragma unroll
  for (int i = 0; i < 12; ++i) {
    float u = __shfl_up(v[i], 1u, 64);
    se[i] = (j == 0) ? 0.f : u;
  }
  if (j == 63) {
#pragma unroll
    for (int i = 0; i < 12; ++i) Tw[w*12 + i] = v[i];
  }
  __syncthreads();
  if (k < 24) {                      // (T0,T1),(T2,T3): M^512*left + right
    int p = k/12, comp = k - p*12;
    Ta[k] = rowdot(cons + OFF_P2 + 6*144 + comp*12, Tw + 2*p*12)
          + Tw[(2*p+1)*12 + comp];
  }
  __syncthreads();
  if (k < 12) {                      // agg[b] = M^1024*Ta0 + Ta1
    agg[b*12 + k] = rowdot(cons + OFF_P2 + 7*144 + k*12, Ta) + Ta[12 + k];
  }
  __threadfence();                   // device-scope: agg visible cross-XCD
  grid.sync();
  // lookback stage 1: slot=4i+jj: lkb[slot] = M^(2048*jj)*agg[b-1-slot]
#pragma unroll
  for (int r = 0; r < 2; ++r) {
    int idx = k + r*BLK;             // covers 384 = 32*12
    if (idx < 384) {
      int slot = idx / 12, comp = idx - slot*12;
      int src = b - 1 - slot;
      float acc = 0.f;
      if (src >= 0) {
        int jj = slot & 3;
        const float* ag = agg + src*12;
        acc = (jj == 0) ? ag[comp]
            : rowdot(cons + OFF_PL + (jj-1)*144 + comp*12, ag);
      }
      lkb[idx] = acc;
    }
  }
  __syncthreads();
  // yv[i] = sum_jj lkb[4i+jj]  (k<96)  |  Pw: P0=0, P1=T0  (k in [192,216))
  if (k < 96) {
    int i = k/12, comp = k - i*12;
    yv[k] = lkb[(4*i)*12+comp] + lkb[(4*i+1)*12+comp]
          + lkb[(4*i+2)*12+comp] + lkb[(4*i+3)*12+comp];
  } else if (k >= 192 && k < 216) {
    int q = k - 192;                 // 0..23
    if (q < 12) Pw[q] = 0.f;         // P0
    else Pw[q] = Tw[q-12];           // P1 = T0
  }
  __syncthreads();
  // zv[i] = M^(8192i)*yv[i] (k<96) | P2 = M^512*P1 + T1 (k in [192,204))
  if (k < 96) {
    int i = k/12, comp = k - i*12;
    zv[k] = (i == 0) ? yv[comp]
          : rowdot(cons + OFF_PD + i*144 + comp*12, yv + i*12);
  } else if (k >= 192 && k < 204) {
    int comp = k - 192;
    Pw[24+comp] = rowdot(cons + OFF_P2 + 6*144 + comp*12, Pw+12) + Tw[12+comp];
  }
  __syncthreads();
  // Xs = sum_i zv[i] (k<12) | P3 = M^512*P2 + T2 (k in [192,204))
  if (k < 12) {
    float s = 0.f;
#pragma unroll
    for (int i = 0; i < 8; ++i) s += zv[i*12 + k];
    Xs[k] = s;
  } else if (k >= 192 && k < 204) {
    int comp = k - 192;
    Pw[36+comp] = rowdot(cons + OFF_P2 + 6*144 + comp*12, Pw+24) + Tw[24+comp];
  }
  __syncthreads();
  // Qw[w] = M^(512w)*Xs + Pw[w]  (w=0..3; matrices I, M^512, M^1024, M^1536)
  if (k < 48) {
    int ww = k/12, comp = k - ww*12;
    float acc;
    if (ww == 0) acc = Xs[comp];
    else if (ww == 1) acc = rowdot(cons + OFF_P2 + 6*144 + comp*12, Xs);
    else if (ww == 2) acc = rowdot(cons + OFF_P2 + 7*144 + comp*12, Xs);
    else acc = rowdot(cons + OFF_PA + comp*12, Xs);
    Qw[k] = acc + Pw[k];
  }
  __syncthreads();
  if (!active) return;               // all barriers (incl. grid.sync) done
  // per-thread: x = M^(8j)*Qw[w] + se   (bits of j, P2[0..5])
  float x[12];
#pragma unroll
  for (int i = 0; i < 12; ++i) x[i] = Qw[w*12 + i];
#pragma unroll
  for (int l = 0; l < 6; ++l) {
    if ((j >> l) & 1) {
      float vn[12];
#pragma unroll
      for (int i = 0; i < 12; ++i) vn[i] = 0.f;
      mv_acc(cons + OFF_P2 + l*144, x, vn);
#pragma unroll
      for (int i = 0; i < 12; ++i) x[i] = vn[i];
    }
  }
#pragma unroll
  for (int i = 0; i < 12; ++i) x[i] += se[i];
  if (b == 0 && k == 0) {
#pragma unroll
    for (int i = 0; i < 12; ++i) x[i] += x0[i];      // start state = x0
#pragma unroll
    for (int i = 0; i < 12; ++i) out[i] = x0[i];     // row 0
  }
  // expand: 8 unconditional steps, predicated stores (NO break)
  float cv[12], av[12], bv[12];
#pragma unroll
  for (int i = 0; i < 12; ++i) {
    cv[i] = cons[OFF_C + i]; av[i] = cons[OFF_AL + i]; bv[i] = cons[OFF_BE + i];
  }
  const float4* Mq = reinterpret_cast<const float4*>(cons + OFF_M);
#pragma unroll
  for (int s = 0; s < CH; ++s) {
    float tot = to_[s], ton = to_[s+1];
    float xn[12];
#pragma unroll
    for (int i = 0; i < 12; ++i) {
      float4 a = Mq[3*i], bq = Mq[3*i+1], c = Mq[3*i+2];
      xn[i] = FMA4(c, x[8],x[9],x[10],x[11],
               FMA4(bq, x[4],x[5],x[6],x[7],
                FMA4(a, x[0],x[1],x[2],x[3],
                 fmaf(bv[i],ton,fmaf(av[i],tot,cv[i])))));
    }
    int tt = base + s;
    if (tt < S_STEPS) {
      float4* op = reinterpret_cast<float4*>(out + (size_t)(tt+1)*12);
      op[0] = make_float4(xn[0],xn[1],xn[2],xn[3]);
      op[1] = make_float4(xn[4],xn[5],xn[6],xn[7]);
      op[2] = make_float4(xn[8],xn[9],xn[10],xn[11]);
    }
#pragma unroll
    for (int i = 0; i < 12; ++i) x[i] = xn[i];
  }
}

extern "C" void kernel_launch(void* const* d_in, const int* in_sizes, int n_in,
                              void* d_out, int out_size, void* d_ws, size_t ws_size,
                              hipStream_t stream) {
  const float* t_eval    = (const float*)d_in[0];
  const float* x0        = (const float*)d_in[1];
  const float* A         = (const float*)d_in[2];
  const float* B         = (const float*)d_in[3];
  const float* To        = (const float*)d_in[4];
  const float* loads_raw = (const float*)d_in[5];
  const float* areas     = (const float*)d_in[6];
  float* out = (float*)d_out;
  float* ws  = (float*)d_ws;

  setup_kernel<<<1, 512, 0, stream>>>(t_eval, A, B, loads_raw, areas, ws);

  const float* cons = ws;
  float* aggp = ws + OFF_AGG;
  void* args[] = { (void*)&cons, (void*)&To, (void*)&x0, (void*)&aggp, (void*)&out };
  hipLaunchCooperativeKernel((const void*)fused_scan, dim3(NB), dim3(BLK),
                             args, 0, stream);
}

// Round 4
// 140.268 us; speedup vs baseline: 1.4580x; 1.4580x over previous
//
#include <hip/hip_runtime.h>
#include <math.h>

// RC thermal model: x' = A x + b0*To(t) + Bq, RK4 h=30, T=1e6 steps.
// Per step: x_{t+1} = M x_t + c + al*To[t] + be*To[t+1].
// R12: revert R11's coop fusion (grid.sync ~50us + non-capturable launch
// ~90us overhead -> 204us total). Back to 3 plain launches (R10 verified
// 132.5us), PLUS stall fix: R10's VGPR_Count=32 showed the compiler
// reloads matrix rows from global inside every matvec row -> ~120cy
// in-order vmcnt round-trip per ROW (~1.4k cy per matvec, ~17 matvecs).
// Fix: batch-preload each 12x12 matrix into float4 Pm[36] registers
// BEFORE the shuffles / step loop; one waitcnt per matvec instead of 12.
// Applied to scan levels (K1+K2), prefix-apply, and expand (M hoisted
// across all 8 steps). Math byte-identical to R10.
// Structure: CH=8, BLK=256, 489 blocks, 3 plain launches.

#define S_STEPS 999999
#define CH      8
#define BLK     256
#define NB      489          // 489*256*8 = 1,001,472 >= S_STEPS
#define NCHUNK  125000       // active chunks (last partial: 7 steps)
#define LASTFULL 124998      // g <= LASTFULL: To[8g+8] in bounds

// ws float offsets (16B-aligned)
#define OFF_M   0            // 144: M
#define OFF_C   144          // 12
#define OFF_AL  156          // 12
#define OFF_BE  168          // 12
#define OFF_K   192          // 120: K cols [col][12], col0 = const (10 cols)
#define OFF_P2  320          // 8*144: [l]=M^(8*2^l) l=0..5 (M^8..M^256),
                             //        [6]=M^512, [7]=M^1024
#define OFF_PA  1472         // 144: M^1536
#define OFF_PL  1616         // 3*144: M^2048, M^4096, M^6144
#define OFF_PD  2048         // 8*144: Pd[i]=M^(8192*i), i=0..7 (Pd[0]=I)
#define OFF_AGG 3200         // 489*12 block aggregates (end 9068 ~ 36 KB)

#define FMA4(Q,a,b,c,d,acc) fmaf((Q).w,(d),fmaf((Q).z,(c),fmaf((Q).y,(b),fmaf((Q).x,(a),(acc)))))

// batch-preload 12x12 row-major matrix (16B-aligned) into registers
__device__ __forceinline__ void mv_pre(const float* Pf, float4* Pm) {
  const float4* P = reinterpret_cast<const float4*>(Pf);
#pragma unroll
  for (int i = 0; i < 36; ++i) Pm[i] = P[i];
}

// y += Pm(registers) * x
__device__ __forceinline__ void mv_apply(const float4* Pm, const float* x, float* y) {
#pragma unroll
  for (int i = 0; i < 12; ++i) {
    y[i] = FMA4(Pm[3*i+2], x[8],x[9],x[10],x[11],
            FMA4(Pm[3*i+1], x[4],x[5],x[6],x[7],
             FMA4(Pm[3*i], x[0],x[1],x[2],x[3], y[i])));
  }
}

// y += P(12x12 row-major, 16B-aligned, global) * x   (cold single-use path)
__device__ __forceinline__ void mv_acc(const float* Pf, const float* x, float* y) {
  float4 Pm[36];
  mv_pre(Pf, Pm);
  mv_apply(Pm, x, y);
}

// dot(P row (16B-aligned), xv[0..11] scalars)
__device__ __forceinline__ float rowdot(const float* Prow, const float* xv) {
  const float4* P = reinterpret_cast<const float4*>(Prow);
  float4 a = P[0], b = P[1], c = P[2];
  return FMA4(c, xv[8],xv[9],xv[10],xv[11],
          FMA4(b, xv[4],xv[5],xv[6],xv[7],
           FMA4(a, xv[0],xv[1],xv[2],xv[3], 0.f)));
}

// v = K[:,0] + sum_{s=0..8} K[:,s+1]*tos[s]
__device__ __forceinline__ void fold_chunk(const float* __restrict__ cons,
                                           const float* tos, float* v) {
  const float4* Kq = reinterpret_cast<const float4*>(cons + OFF_K);
  float4 Kr[30];
#pragma unroll
  for (int i = 0; i < 30; ++i) Kr[i] = Kq[i];   // batch: one waitcnt
  v[0]=Kr[0].x; v[1]=Kr[0].y; v[2]=Kr[0].z; v[3]=Kr[0].w;
  v[4]=Kr[1].x; v[5]=Kr[1].y; v[6]=Kr[1].z; v[7]=Kr[1].w;
  v[8]=Kr[2].x; v[9]=Kr[2].y; v[10]=Kr[2].z; v[11]=Kr[2].w;
#pragma unroll
  for (int s = 0; s < 9; ++s) {
    float ts = tos[s];
    float4 ka=Kr[3*(s+1)], kb=Kr[3*(s+1)+1], kc=Kr[3*(s+1)+2];
    v[0]=fmaf(ka.x,ts,v[0]); v[1]=fmaf(ka.y,ts,v[1]); v[2]=fmaf(ka.z,ts,v[2]); v[3]=fmaf(ka.w,ts,v[3]);
    v[4]=fmaf(kb.x,ts,v[4]); v[5]=fmaf(kb.y,ts,v[5]); v[6]=fmaf(kb.z,ts,v[6]); v[7]=fmaf(kb.w,ts,v[7]);
    v[8]=fmaf(kc.x,ts,v[8]); v[9]=fmaf(kc.y,ts,v[9]); v[10]=fmaf(kc.z,ts,v[10]); v[11]=fmaf(kc.w,ts,v[11]);
  }
}

__global__ void __launch_bounds__(512) setup_kernel(
    const float* __restrict__ t_eval, const float* __restrict__ A,
    const float* __restrict__ Bm, const float* __restrict__ loads_raw,
    const float* __restrict__ areas, float* ws) {
  __shared__ double H1[144], H2[144], H3[144], H4[144], Md[144];
  __shared__ double Qa[144], Qb[144];
  __shared__ double C512s[144], C1024s[144], C2048s[144], C4096s[144];
  __shared__ double C8192s[144], C16384s[144], C32768s[144], Pd3s[144];
  __shared__ double cd[12], ald[12], bed[12], b0d[12], bqd[12];
  __shared__ double Vv[3][12], Kd[120];
  int t = threadIdx.x;
  double h = (double)t_eval[1] - (double)t_eval[0];
  if (t < 144) H1[t] = h * (double)A[t];
  if (t < 12) {
    b0d[t] = (double)Bm[t*11];
    double s = 0.0;
    for (int r = 0; r < 10; ++r) {
      double gq = 50.0 / (1.0 + exp(-(double)loads_raw[10 + r]));
      s += (double)Bm[t*11 + 1 + r] * (gq * (double)areas[r]);
    }
    bqd[t] = s;
  }
  if (t < 120) Kd[t] = 0.0;
  __syncthreads();
  if (t < 144) {                              // H2 = H1*H1
    int i=t/12, j=t%12; double s=0.0;
#pragma unroll
    for (int m = 0; m < 12; ++m) s += H1[i*12+m]*H1[m*12+j];
    H2[t]=s;
  }
  __syncthreads();
  if (t < 288) {                              // H3 = H2*H1 | H4 = H2*H2
    int w=t/144, e=t%144, i=e/12, j=e%12;
    const double* Bp = w ? H2 : H1;
    double s = 0.0;
#pragma unroll
    for (int m = 0; m < 12; ++m) s += H2[i*12+m]*Bp[m*12+j];
    (w ? H4 : H3)[e] = s;
  }
  __syncthreads();
  if (t < 12) {
    double hb=0,h2b=0,h3b=0,hb0=0,h2b0=0,h3b0=0;
#pragma unroll
    for (int m = 0; m < 12; ++m) {
      hb  += H1[t*12+m]*bqd[m]; h2b  += H2[t*12+m]*bqd[m]; h3b  += H3[t*12+m]*bqd[m];
      hb0 += H1[t*12+m]*b0d[m]; h2b0 += H2[t*12+m]*b0d[m]; h3b0 += H3[t*12+m]*b0d[m];
    }
    double h6 = h / 6.0;
    cd[t]  = h6*(6.0*bqd[t] + 3.0*hb + h2b + 0.25*h3b);
    ald[t] = h6*(3.0*b0d[t] + 2.0*hb0 + 0.75*h2b0 + 0.25*h3b0);
    bed[t] = h6*(3.0*b0d[t] + hb0 + 0.25*h2b0);
    Vv[0][t]=ald[t]; Vv[1][t]=bed[t]; Vv[2][t]=cd[t];
    // r=0 K contributions (CH=8): col8 += al, col9 += be, col0 += c
    Kd[96+t] += ald[t]; Kd[108+t] += bed[t]; Kd[t] += cd[t];
  }
  if (t >= 144 && t < 288) {
    int e=t-144, i=e/12, j=e%12;
    Md[e] = (i==j ? 1.0 : 0.0) + H1[e] + 0.5*H2[e] + H3[e]/6.0 + H4[e]/24.0;
  }
  __syncthreads();
  if (t < 144) { ws[OFF_M+t] = (float)Md[t]; Qa[t] = Md[t]; }
  if (t < 12) {
    ws[OFF_C+t]=(float)cd[t]; ws[OFF_AL+t]=(float)ald[t]; ws[OFF_BE+t]=(float)bed[t];
  }
  __syncthreads();
  // chain r=1..15: src=M^(2^(r-1)) -> dst=M^(2^r). Overlapped K rounds
  // r=1..7 (threads 256..291): Vv=M^r*{al,be,c}; Kd cols (8-r),(9-r),0.
  double* src = Qa; double* dst = Qb;
  for (int r = 1; r <= 15; ++r) {
    double acc = 0.0, ks = 0.0;
    if (t < 144) {
      int i=t/12, j=t%12;
#pragma unroll
      for (int m = 0; m < 12; ++m) acc += src[i*12+m]*src[m*12+j];
    }
    int w=0, i2=0;
    if (r <= 7 && t >= 256 && t < 292) {
      w=(t-256)/12; i2=(t-256)%12;
#pragma unroll
      for (int m = 0; m < 12; ++m) ks += Md[i2*12+m]*Vv[w][m];
    }
    __syncthreads();
    if (t < 144) {
      dst[t] = acc;
      if (r >= 3 && r <= 10) ws[OFF_P2+(r-3)*144+t] = (float)acc;  // M^8..M^1024
      if (r == 9)  C512s[t]=acc;
      if (r == 10) C1024s[t]=acc;
      if (r == 11) { C2048s[t]=acc;  ws[OFF_PL+t]       = (float)acc; }
      if (r == 12) { C4096s[t]=acc;  ws[OFF_PL+144+t]   = (float)acc; }
      if (r == 13) { C8192s[t]=acc;  ws[OFF_PD+144+t]   = (float)acc; }  // Pd[1]
      if (r == 14) { C16384s[t]=acc; ws[OFF_PD+2*144+t] = (float)acc; }  // Pd[2]
      if (r == 15) { C32768s[t]=acc; ws[OFF_PD+4*144+t] = (float)acc; }  // Pd[4]
    }
    if (r <= 7 && t >= 256 && t < 292) {
      Vv[w][i2] = ks;
      if (w == 0) Kd[(8-r)*12+i2] += ks;
      else if (w == 1) Kd[(9-r)*12+i2] += ks;
      else Kd[i2] += ks;
    }
    __syncthreads();
    double* tmp = src; src = dst; dst = tmp;    // src = M^(2^r)
  }
  if (t < 120) ws[OFF_K+t] = (float)Kd[t];
  if (t < 144) ws[OFF_PD+t] = (t % 13 == 0) ? 1.f : 0.f;   // Pd[0]=I
  // product round A: M^1536=M^512*M^1024 ; M^6144=M^2048*M^4096 ;
  //                  Pd[3]=M^8192*M^16384
  if (t < 432) {
    int w=t/144, e=t%144, i=e/12, j=e%12;
    const double* Ap = (w==0) ? C512s  : ((w==1) ? C2048s : C8192s);
    const double* Bp = (w==0) ? C1024s : ((w==1) ? C4096s : C16384s);
    double s = 0.0;
#pragma unroll
    for (int m = 0; m < 12; ++m) s += Ap[i*12+m]*Bp[m*12+j];
    if (w==0) ws[OFF_PA+e] = (float)s;
    else if (w==1) ws[OFF_PL+2*144+e] = (float)s;
    else { ws[OFF_PD+3*144+e] = (float)s; Pd3s[e] = s; }
  }
  __syncthreads();
  // product round B: Pd[5]=Pd[1]*M^32768 ; Pd[6]=Pd[2]*M^32768 ;
  //                  Pd[7]=Pd[3]*M^32768
  if (t < 432) {
    int w=t/144, e=t%144, i=e/12, j=e%12;
    const double* Ap = (w==0) ? C8192s : ((w==1) ? C16384s : Pd3s);
    double s = 0.0;
#pragma unroll
    for (int m = 0; m < 12; ++m) s += Ap[i*12+m]*C32768s[m*12+j];
    ws[OFF_PD+(5+w)*144+e] = (float)s;
  }
}

// K1: block aggregate (2048 steps) = wave shfl-scan (6 levels, preloaded
// level matrices) + 2-level LDS tree over 4 wave totals.
__global__ void __launch_bounds__(BLK, 2) block_agg(
    const float* __restrict__ cons, const float* __restrict__ To,
    const float* __restrict__ x0, float* __restrict__ agg) {
  __shared__ __align__(16) float Tw[48], Ta[24];
  int k = threadIdx.x, b = blockIdx.x;
  int g = b*BLK + k, base = g*CH;
  bool fullc = (g <= LASTFULL);
  float to_[9];
#pragma unroll
  for (int i = 0; i < 9; ++i) to_[i] = 0.f;
  if (fullc) {
    const float4* tp = reinterpret_cast<const float4*>(To + base);
    float4 ta = tp[0], tb = tp[1];
    to_[0]=ta.x; to_[1]=ta.y; to_[2]=ta.z; to_[3]=ta.w;
    to_[4]=tb.x; to_[5]=tb.y; to_[6]=tb.z; to_[7]=tb.w;
    to_[8]=To[base+8];
  }
  float v[12];
  if (fullc) fold_chunk(cons, to_, v);
  else {
#pragma unroll
    for (int i = 0; i < 12; ++i) v[i] = 0.f;
  }
  if (g == 0) {                      // fold x0 into chunk 0: v += M^8 x0
    float xi[12];
#pragma unroll
    for (int i = 0; i < 12; ++i) xi[i] = x0[i];
    mv_acc(cons + OFF_P2, xi, v);
  }
  int j = k & 63;
#pragma unroll
  for (int l = 0; l < 6; ++l) {      // in-wave inclusive scan
    int off = 1 << l;
    float4 Pm[36];
    mv_pre(cons + OFF_P2 + l*144, Pm);   // issue loads (vmcnt) ...
    float nb[12];
#pragma unroll
    for (int i = 0; i < 12; ++i)         // ... overlap with shuffles (lgkm)
      nb[i] = __shfl_up(v[i], (unsigned)off, 64);
    if (j >= off) mv_apply(Pm, nb, v);
  }
  if (j == 63) {
#pragma unroll
    for (int i = 0; i < 12; ++i) Tw[(k>>6)*12 + i] = v[i];
  }
  __syncthreads();
  if (k < 24) {                      // (T0,T1),(T2,T3): M^512*left + right
    int p = k/12, comp = k - p*12;
    Ta[k] = rowdot(cons + OFF_P2 + 6*144 + comp*12, Tw + 2*p*12)
          + Tw[(2*p+1)*12 + comp];
  }
  __syncthreads();
  if (k < 12) {                      // M^1024*Ta0 + Ta1
    agg[b*12 + k] = rowdot(cons + OFF_P2 + 7*144 + k*12, Ta) + Ta[12 + k];
  }
}

// K2: fold + wave scan (exclusive) + truncated 32-block lookback + merged
// prefix apply + 8-step expand (M register-hoisted across steps).
__global__ void __launch_bounds__(BLK, 2) scan_expand(
    const float* __restrict__ cons, const float* __restrict__ To,
    const float* __restrict__ x0, const float* __restrict__ agg,
    float* __restrict__ out) {
  __shared__ __align__(16) float Tw[48];      // wave totals
  __shared__ __align__(16) float Pw[48];      // wave exclusive prefixes
  __shared__ __align__(16) float lkb[32*12];  // lookback stage-1 partials
  __shared__ __align__(16) float yv[8*12];
  __shared__ __align__(16) float zv[8*12];
  __shared__ __align__(16) float Xs[12];
  __shared__ __align__(16) float Qw[48];      // M^(512w)*Xs + Pw
  int k = threadIdx.x, b = blockIdx.x;
  int g = b*BLK + k, base = g*CH;
  bool active = (g < NCHUNK), fullc = (g <= LASTFULL);
  float to_[9];
#pragma unroll
  for (int i = 0; i < 9; ++i) to_[i] = 0.f;
  if (active) {
    const float4* tp = reinterpret_cast<const float4*>(To + base);
    float4 ta = tp[0], tb = tp[1];
    to_[0]=ta.x; to_[1]=ta.y; to_[2]=ta.z; to_[3]=ta.w;
    to_[4]=tb.x; to_[5]=tb.y; to_[6]=tb.z; to_[7]=tb.w;
    to_[8] = fullc ? To[base+8] : 0.f;
  }
  float v[12];
  if (fullc) fold_chunk(cons, to_, v);
  else {
#pragma unroll
    for (int i = 0; i < 12; ++i) v[i] = 0.f;
  }
  if (g == 0) {
    float xi[12];
#pragma unroll
    for (int i = 0; i < 12; ++i) xi[i] = x0[i];
    mv_acc(cons + OFF_P2, xi, v);
  }
  int j = k & 63, w = k >> 6;
#pragma unroll
  for (int l = 0; l < 6; ++l) {      // in-wave inclusive scan
    int off = 1 << l;
    float4 Pm[36];
    mv_pre(cons + OFF_P2 + l*144, Pm);   // issue loads (vmcnt) ...
    float nb[12];
#pragma unroll
    for (int i = 0; i < 12; ++i)         // ... overlap with shuffles (lgkm)
      nb[i] = __shfl_up(v[i], (unsigned)off, 64);
    if (j >= off) mv_apply(Pm, nb, v);
  }
  float se[12];                      // exclusive in-wave scan
#pragma unroll
  for (int i = 0; i < 12; ++i) {
    float u = __shfl_up(v[i], 1u, 64);
    se[i] = (j == 0) ? 0.f : u;
  }
  if (j == 63) {
#pragma unroll
    for (int i = 0; i < 12; ++i) Tw[w*12 + i] = v[i];
  }
  // lookback stage 1 (before barrier): slot=4i+jj:
  // lkb[slot] = M^(2048*jj)*agg[b-1-slot]
#pragma unroll
  for (int r = 0; r < 2; ++r) {
    int idx = k + r*BLK;             // covers 384 = 32*12
    if (idx < 384) {
      int slot = idx / 12, comp = idx - slot*12;
      int src = b - 1 - slot;
      float acc = 0.f;
      if (src >= 0) {
        int jj = slot & 3;
        const float* ag = agg + src*12;
        acc = (jj == 0) ? ag[comp]
            : rowdot(cons + OFF_PL + (jj-1)*144 + comp*12, ag);
      }
      lkb[idx] = acc;
    }
  }
  __syncthreads();
  // yv[i] = sum_jj lkb[4i+jj]  (k<96)  |  Pw: P0=0, P1=T0  (k in [192,216))
  if (k < 96) {
    int i = k/12, comp = k - i*12;
    yv[k] = lkb[(4*i)*12+comp] + lkb[(4*i+1)*12+comp]
          + lkb[(4*i+2)*12+comp] + lkb[(4*i+3)*12+comp];
  } else if (k >= 192 && k < 216) {
    int q = k - 192;                 // 0..23
    if (q < 12) Pw[q] = 0.f;         // P0
    else Pw[q] = Tw[q-12];           // P1 = T0
  }
  __syncthreads();
  // zv[i] = M^(8192i)*yv[i] (k<96) | P2 = M^512*P1 + T1 (k in [192,204))
  if (k < 96) {
    int i = k/12, comp = k - i*12;
    zv[k] = (i == 0) ? yv[comp]
          : rowdot(cons + OFF_PD + i*144 + comp*12, yv + i*12);
  } else if (k >= 192 && k < 204) {
    int comp = k - 192;
    Pw[24+comp] = rowdot(cons + OFF_P2 + 6*144 + comp*12, Pw+12) + Tw[12+comp];
  }
  __syncthreads();
  // Xs = sum_i zv[i] (k<12) | P3 = M^512*P2 + T2 (k in [192,204))
  if (k < 12) {
    float s = 0.f;
#pragma unroll
    for (int i = 0; i < 8; ++i) s += zv[i*12 + k];
    Xs[k] = s;
  } else if (k >= 192 && k < 204) {
    int comp = k - 192;
    Pw[36+comp] = rowdot(cons + OFF_P2 + 6*144 + comp*12, Pw+24) + Tw[24+comp];
  }
  __syncthreads();
  // Qw[w] = M^(512w)*Xs + Pw[w]  (w=0..3; matrices I, M^512, M^1024, M^1536)
  if (k < 48) {
    int ww = k/12, comp = k - ww*12;
    float acc;
    if (ww == 0) acc = Xs[comp];
    else if (ww == 1) acc = rowdot(cons + OFF_P2 + 6*144 + comp*12, Xs);
    else if (ww == 2) acc = rowdot(cons + OFF_P2 + 7*144 + comp*12, Xs);
    else acc = rowdot(cons + OFF_PA + comp*12, Xs);
    Qw[k] = acc + Pw[k];
  }
  __syncthreads();
  if (!active) return;               // all barriers done
  // per-thread: x = M^(8j)*Qw[w] + se   (bits of j, P2[0..5])
  float x[12];
#pragma unroll
  for (int i = 0; i < 12; ++i) x[i] = Qw[w*12 + i];
#pragma unroll
  for (int l = 0; l < 6; ++l) {
    if ((j >> l) & 1) {
      float4 Pm[36];
      mv_pre(cons + OFF_P2 + l*144, Pm);
      float vn[12];
#pragma unroll
      for (int i = 0; i < 12; ++i) vn[i] = 0.f;
      mv_apply(Pm, x, vn);
#pragma unroll
      for (int i = 0; i < 12; ++i) x[i] = vn[i];
    }
  }
#pragma unroll
  for (int i = 0; i < 12; ++i) x[i] += se[i];
  if (b == 0 && k == 0) {
#pragma unroll
    for (int i = 0; i < 12; ++i) x[i] += x0[i];      // start state = x0
#pragma unroll
    for (int i = 0; i < 12; ++i) out[i] = x0[i];     // row 0
  }
  // expand: 8 unconditional steps, predicated stores (NO break).
  // M, c, al, be register-hoisted across all steps.
  float cv[12], av[12], bv[12];
#pragma unroll
  for (int i = 0; i < 12; ++i) {
    cv[i] = cons[OFF_C + i]; av[i] = cons[OFF_AL + i]; bv[i] = cons[OFF_BE + i];
  }
  float4 Mr[36];
  mv_pre(cons + OFF_M, Mr);
#pragma unroll
  for (int s = 0; s < CH; ++s) {
    float tot = to_[s], ton = to_[s+1];
    float xn[12];
#pragma unroll
    for (int i = 0; i < 12; ++i) {
      xn[i] = FMA4(Mr[3*i+2], x[8],x[9],x[10],x[11],
               FMA4(Mr[3*i+1], x[4],x[5],x[6],x[7],
                FMA4(Mr[3*i], x[0],x[1],x[2],x[3],
                 fmaf(bv[i],ton,fmaf(av[i],tot,cv[i])))));
    }
    int tt = base + s;
    if (tt < S_STEPS) {
      float4* op = reinterpret_cast<float4*>(out + (size_t)(tt+1)*12);
      op[0] = make_float4(xn[0],xn[1],xn[2],xn[3]);
      op[1] = make_float4(xn[4],xn[5],xn[6],xn[7]);
      op[2] = make_float4(xn[8],xn[9],xn[10],xn[11]);
    }
#pragma unroll
    for (int i = 0; i < 12; ++i) x[i] = xn[i];
  }
}

extern "C" void kernel_launch(void* const* d_in, const int* in_sizes, int n_in,
                              void* d_out, int out_size, void* d_ws, size_t ws_size,
                              hipStream_t stream) {
  const float* t_eval    = (const float*)d_in[0];
  const float* x0        = (const float*)d_in[1];
  const float* A         = (const float*)d_in[2];
  const float* B         = (const float*)d_in[3];
  const float* To        = (const float*)d_in[4];
  const float* loads_raw = (const float*)d_in[5];
  const float* areas     = (const float*)d_in[6];
  float* out = (float*)d_out;
  float* ws  = (float*)d_ws;

  setup_kernel<<<1, 512, 0, stream>>>(t_eval, A, B, loads_raw, areas, ws);
  block_agg<<<NB, BLK, 0, stream>>>(ws, To, x0, ws + OFF_AGG);
  scan_expand<<<NB, BLK, 0, stream>>>(ws, To, x0, ws + OFF_AGG, out);
}

// Round 5
// 135.469 us; speedup vs baseline: 1.5096x; 1.0354x over previous
//
#include <hip/hip_runtime.h>
#include <math.h>

// RC thermal model: x' = A x + b0*To(t) + Bq, RK4 h=30, T=1e6 steps.
// Per step: x_{t+1} = M x_t + c + al*To[t] + be*To[t+1].
// R13: fused K1+K2 via DECOUPLED LOOKBACK (publish/spin), plain launch.
// R11 decomposition: grid.sync cost ~50us (fused 96.6 vs K2 43.8);
// R12 lesson: register-preload demotes to scratch (VGPR stuck at 32,
// WRITE +13MB, 2x slower) -- all device bodies reverted to R10 forms.
// Here: block b publishes agg[b] (relaxed agent stores + release flag),
// spins only on flags[b-32..b-1] (acquire + s_sleep). 489 blocks all
// co-resident (VGPR 32, LDS 3KB); preds publish before spinning => no
// deadlock. Flags zeroed by setup each iteration (ws is re-poisoned).
// Structure: setup (plain) + fused_scan (plain). CH=8, BLK=256, NB=489.

#define S_STEPS 999999
#define CH      8
#define BLK     256
#define NB      489          // 489*256*8 = 1,001,472 >= S_STEPS
#define NCHUNK  125000       // active chunks (last partial: 7 steps)
#define LASTFULL 124998      // g <= LASTFULL: To[8g+8] in bounds

// ws float offsets (16B-aligned)
#define OFF_M   0            // 144: M
#define OFF_C   144          // 12
#define OFF_AL  156          // 12
#define OFF_BE  168          // 12
#define OFF_K   192          // 120: K cols [col][12], col0 = const (10 cols)
#define OFF_P2  320          // 8*144: [l]=M^(8*2^l) l=0..5 (M^8..M^256),
                             //        [6]=M^512, [7]=M^1024
#define OFF_PA  1472         // 144: M^1536
#define OFF_PL  1616         // 3*144: M^2048, M^4096, M^6144
#define OFF_PD  2048         // 8*144: Pd[i]=M^(8192*i), i=0..7 (Pd[0]=I)
#define OFF_AGG 3200         // 489*12 block aggregates (end 9068)
#define OFF_FLAG 9072        // 489 int flags (16B-aligned)

#define FMA4(Q,a,b,c,d,acc) fmaf((Q).w,(d),fmaf((Q).z,(c),fmaf((Q).y,(b),fmaf((Q).x,(a),(acc)))))

// y += P(12x12 row-major, 16B-aligned) * x
__device__ __forceinline__ void mv_acc(const float* Pf, const float* x, float* y) {
  const float4* P = reinterpret_cast<const float4*>(Pf);
#pragma unroll
  for (int i = 0; i < 12; ++i) {
    float4 a = P[3*i], b = P[3*i+1], c = P[3*i+2];
    y[i] = FMA4(c, x[8],x[9],x[10],x[11],
            FMA4(b, x[4],x[5],x[6],x[7],
             FMA4(a, x[0],x[1],x[2],x[3], y[i])));
  }
}

// dot(P row (16B-aligned), xv[0..11] scalars)
__device__ __forceinline__ float rowdot(const float* Prow, const float* xv) {
  const float4* P = reinterpret_cast<const float4*>(Prow);
  float4 a = P[0], b = P[1], c = P[2];
  return FMA4(c, xv[8],xv[9],xv[10],xv[11],
          FMA4(b, xv[4],xv[5],xv[6],xv[7],
           FMA4(a, xv[0],xv[1],xv[2],xv[3], 0.f)));
}

// v = K[:,0] + sum_{s=0..8} K[:,s+1]*tos[s]
__device__ __forceinline__ void fold_chunk(const float* __restrict__ cons,
                                           const float* tos, float* v) {
  const float4* Kq = reinterpret_cast<const float4*>(cons + OFF_K);
  float4 c0=Kq[0], c1=Kq[1], c2=Kq[2];
  v[0]=c0.x; v[1]=c0.y; v[2]=c0.z; v[3]=c0.w;
  v[4]=c1.x; v[5]=c1.y; v[6]=c1.z; v[7]=c1.w;
  v[8]=c2.x; v[9]=c2.y; v[10]=c2.z; v[11]=c2.w;
#pragma unroll
  for (int s = 0; s < 9; ++s) {
    float ts = tos[s];
    float4 ka=Kq[3*(s+1)], kb=Kq[3*(s+1)+1], kc=Kq[3*(s+1)+2];
    v[0]=fmaf(ka.x,ts,v[0]); v[1]=fmaf(ka.y,ts,v[1]); v[2]=fmaf(ka.z,ts,v[2]); v[3]=fmaf(ka.w,ts,v[3]);
    v[4]=fmaf(kb.x,ts,v[4]); v[5]=fmaf(kb.y,ts,v[5]); v[6]=fmaf(kb.z,ts,v[6]); v[7]=fmaf(kb.w,ts,v[7]);
    v[8]=fmaf(kc.x,ts,v[8]); v[9]=fmaf(kc.y,ts,v[9]); v[10]=fmaf(kc.z,ts,v[10]); v[11]=fmaf(kc.w,ts,v[11]);
  }
}

__global__ void __launch_bounds__(512) setup_kernel(
    const float* __restrict__ t_eval, const float* __restrict__ A,
    const float* __restrict__ Bm, const float* __restrict__ loads_raw,
    const float* __restrict__ areas, float* ws) {
  __shared__ double H1[144], H2[144], H3[144], H4[144], Md[144];
  __shared__ double Qa[144], Qb[144];
  __shared__ double C512s[144], C1024s[144], C2048s[144], C4096s[144];
  __shared__ double C8192s[144], C16384s[144], C32768s[144], Pd3s[144];
  __shared__ double cd[12], ald[12], bed[12], b0d[12], bqd[12];
  __shared__ double Vv[3][12], Kd[120];
  int t = threadIdx.x;
  if (t < NB) ((int*)(ws + OFF_FLAG))[t] = 0;   // reset lookback flags
  double h = (double)t_eval[1] - (double)t_eval[0];
  if (t < 144) H1[t] = h * (double)A[t];
  if (t < 12) {
    b0d[t] = (double)Bm[t*11];
    double s = 0.0;
    for (int r = 0; r < 10; ++r) {
      double gq = 50.0 / (1.0 + exp(-(double)loads_raw[10 + r]));
      s += (double)Bm[t*11 + 1 + r] * (gq * (double)areas[r]);
    }
    bqd[t] = s;
  }
  if (t < 120) Kd[t] = 0.0;
  __syncthreads();
  if (t < 144) {                              // H2 = H1*H1
    int i=t/12, j=t%12; double s=0.0;
#pragma unroll
    for (int m = 0; m < 12; ++m) s += H1[i*12+m]*H1[m*12+j];
    H2[t]=s;
  }
  __syncthreads();
  if (t < 288) {                              // H3 = H2*H1 | H4 = H2*H2
    int w=t/144, e=t%144, i=e/12, j=e%12;
    const double* Bp = w ? H2 : H1;
    double s = 0.0;
#pragma unroll
    for (int m = 0; m < 12; ++m) s += H2[i*12+m]*Bp[m*12+j];
    (w ? H4 : H3)[e] = s;
  }
  __syncthreads();
  if (t < 12) {
    double hb=0,h2b=0,h3b=0,hb0=0,h2b0=0,h3b0=0;
#pragma unroll
    for (int m = 0; m < 12; ++m) {
      hb  += H1[t*12+m]*bqd[m]; h2b  += H2[t*12+m]*bqd[m]; h3b  += H3[t*12+m]*bqd[m];
      hb0 += H1[t*12+m]*b0d[m]; h2b0 += H2[t*12+m]*b0d[m]; h3b0 += H3[t*12+m]*b0d[m];
    }
    double h6 = h / 6.0;
    cd[t]  = h6*(6.0*bqd[t] + 3.0*hb + h2b + 0.25*h3b);
    ald[t] = h6*(3.0*b0d[t] + 2.0*hb0 + 0.75*h2b0 + 0.25*h3b0);
    bed[t] = h6*(3.0*b0d[t] + hb0 + 0.25*h2b0);
    Vv[0][t]=ald[t]; Vv[1][t]=bed[t]; Vv[2][t]=cd[t];
    // r=0 K contributions (CH=8): col8 += al, col9 += be, col0 += c
    Kd[96+t] += ald[t]; Kd[108+t] += bed[t]; Kd[t] += cd[t];
  }
  if (t >= 144 && t < 288) {
    int e=t-144, i=e/12, j=e%12;
    Md[e] = (i==j ? 1.0 : 0.0) + H1[e] + 0.5*H2[e] + H3[e]/6.0 + H4[e]/24.0;
  }
  __syncthreads();
  if (t < 144) { ws[OFF_M+t] = (float)Md[t]; Qa[t] = Md[t]; }
  if (t < 12) {
    ws[OFF_C+t]=(float)cd[t]; ws[OFF_AL+t]=(float)ald[t]; ws[OFF_BE+t]=(float)bed[t];
  }
  __syncthreads();
  // chain r=1..15: src=M^(2^(r-1)) -> dst=M^(2^r). Overlapped K rounds
  // r=1..7 (threads 256..291): Vv=M^r*{al,be,c}; Kd cols (8-r),(9-r),0.
  double* src = Qa; double* dst = Qb;
  for (int r = 1; r <= 15; ++r) {
    double acc = 0.0, ks = 0.0;
    if (t < 144) {
      int i=t/12, j=t%12;
#pragma unroll
      for (int m = 0; m < 12; ++m) acc += src[i*12+m]*src[m*12+j];
    }
    int w=0, i2=0;
    if (r <= 7 && t >= 256 && t < 292) {
      w=(t-256)/12; i2=(t-256)%12;
#pragma unroll
      for (int m = 0; m < 12; ++m) ks += Md[i2*12+m]*Vv[w][m];
    }
    __syncthreads();
    if (t < 144) {
      dst[t] = acc;
      if (r >= 3 && r <= 10) ws[OFF_P2+(r-3)*144+t] = (float)acc;  // M^8..M^1024
      if (r == 9)  C512s[t]=acc;
      if (r == 10) C1024s[t]=acc;
      if (r == 11) { C2048s[t]=acc;  ws[OFF_PL+t]       = (float)acc; }
      if (r == 12) { C4096s[t]=acc;  ws[OFF_PL+144+t]   = (float)acc; }
      if (r == 13) { C8192s[t]=acc;  ws[OFF_PD+144+t]   = (float)acc; }  // Pd[1]
      if (r == 14) { C16384s[t]=acc; ws[OFF_PD+2*144+t] = (float)acc; }  // Pd[2]
      if (r == 15) { C32768s[t]=acc; ws[OFF_PD+4*144+t] = (float)acc; }  // Pd[4]
    }
    if (r <= 7 && t >= 256 && t < 292) {
      Vv[w][i2] = ks;
      if (w == 0) Kd[(8-r)*12+i2] += ks;
      else if (w == 1) Kd[(9-r)*12+i2] += ks;
      else Kd[i2] += ks;
    }
    __syncthreads();
    double* tmp = src; src = dst; dst = tmp;    // src = M^(2^r)
  }
  if (t < 120) ws[OFF_K+t] = (float)Kd[t];
  if (t < 144) ws[OFF_PD+t] = (t % 13 == 0) ? 1.f : 0.f;   // Pd[0]=I
  // product round A: M^1536=M^512*M^1024 ; M^6144=M^2048*M^4096 ;
  //                  Pd[3]=M^8192*M^16384
  if (t < 432) {
    int w=t/144, e=t%144, i=e/12, j=e%12;
    const double* Ap = (w==0) ? C512s  : ((w==1) ? C2048s : C8192s);
    const double* Bp = (w==0) ? C1024s : ((w==1) ? C4096s : C16384s);
    double s = 0.0;
#pragma unroll
    for (int m = 0; m < 12; ++m) s += Ap[i*12+m]*Bp[m*12+j];
    if (w==0) ws[OFF_PA+e] = (float)s;
    else if (w==1) ws[OFF_PL+2*144+e] = (float)s;
    else { ws[OFF_PD+3*144+e] = (float)s; Pd3s[e] = s; }
  }
  __syncthreads();
  // product round B: Pd[5]=Pd[1]*M^32768 ; Pd[6]=Pd[2]*M^32768 ;
  //                  Pd[7]=Pd[3]*M^32768
  if (t < 432) {
    int w=t/144, e=t%144, i=e/12, j=e%12;
    const double* Ap = (w==0) ? C8192s : ((w==1) ? C16384s : Pd3s);
    double s = 0.0;
#pragma unroll
    for (int m = 0; m < 12; ++m) s += Ap[i*12+m]*C32768s[m*12+j];
    ws[OFF_PD+(5+w)*144+e] = (float)s;
  }
}

// Fused: fold+scan ONCE; publish agg[b] (release flag); spin on 32
// predecessor flags (acquire); truncated lookback + merged prefix +
// 8-step expand. Plain launch, graph-capturable.
__global__ void __launch_bounds__(BLK, 2) fused_scan(
    const float* __restrict__ cons, const float* __restrict__ To,
    const float* __restrict__ x0, float* __restrict__ agg,
    int* __restrict__ flags, float* __restrict__ out) {
  __shared__ __align__(16) float Tw[48];      // wave totals
  __shared__ __align__(16) float Ta[24];      // agg tree level 1
  __shared__ __align__(16) float Pw[48];      // wave exclusive prefixes
  __shared__ __align__(16) float lkb[32*12];  // lookback stage-1 partials
  __shared__ __align__(16) float yv[8*12];
  __shared__ __align__(16) float zv[8*12];
  __shared__ __align__(16) float Xs[12];
  __shared__ __align__(16) float Qw[48];      // M^(512w)*Xs + Pw
  int k = threadIdx.x, b = blockIdx.x;
  int g = b*BLK + k, base = g*CH;
  bool active = (g < NCHUNK), fullc = (g <= LASTFULL);
  float to_[9];
#pragma unroll
  for (int i = 0; i < 9; ++i) to_[i] = 0.f;
  if (active) {
    const float4* tp = reinterpret_cast<const float4*>(To + base);
    float4 ta = tp[0], tb = tp[1];
    to_[0]=ta.x; to_[1]=ta.y; to_[2]=ta.z; to_[3]=ta.w;
    to_[4]=tb.x; to_[5]=tb.y; to_[6]=tb.z; to_[7]=tb.w;
    to_[8] = fullc ? To[base+8] : 0.f;
  }
  float v[12];
  if (fullc) fold_chunk(cons, to_, v);
  else {
#pragma unroll
    for (int i = 0; i < 12; ++i) v[i] = 0.f;
  }
  if (g == 0) {                      // fold x0 into chunk 0: v += M^8 x0
    float xi[12];
#pragma unroll
    for (int i = 0; i < 12; ++i) xi[i] = x0[i];
    mv_acc(cons + OFF_P2, xi, v);
  }
  int j = k & 63, w = k >> 6;
#pragma unroll
  for (int l = 0; l < 6; ++l) {      // in-wave inclusive scan
    int off = 1 << l;
    float nb[12];
#pragma unroll
    for (int i = 0; i < 12; ++i) nb[i] = __shfl_up(v[i], (unsigned)off, 64);
    if (j >= off) mv_acc(cons + OFF_P2 + l*144, nb, v);
  }
  float se[12];                      // exclusive in-wave scan
#pragma unroll
  for (int i = 0; i < 12; ++i) {
    float u = __shfl_up(v[i], 1u, 64);
    se[i] = (j == 0) ? 0.f : u;
  }
  if (j == 63) {
#pragma unroll
    for (int i = 0; i < 12; ++i) Tw[w*12 + i] = v[i];
  }
  __syncthreads();
  if (k < 24) {                      // (T0,T1),(T2,T3): M^512*left + right
    int p = k/12, comp = k - p*12;
    Ta[k] = rowdot(cons + OFF_P2 + 6*144 + comp*12, Tw + 2*p*12)
          + Tw[(2*p+1)*12 + comp];
  }
  __syncthreads();
  if (k < 12) {                      // agg[b] = M^1024*Ta0 + Ta1 (agent)
    float val = rowdot(cons + OFF_P2 + 7*144 + k*12, Ta) + Ta[12 + k];
    __hip_atomic_store(&agg[b*12 + k], val, __ATOMIC_RELAXED,
                       __HIP_MEMORY_SCOPE_AGENT);
  }
  __syncthreads();
  if (k == 0)                        // publish: release flag
    __hip_atomic_store(&flags[b], 1, __ATOMIC_RELEASE,
                       __HIP_MEMORY_SCOPE_AGENT);
  // spin on 32 predecessors (threads k<32, one flag each)
  if (k < 32) {
    int src = b - 1 - k;
    if (src >= 0) {
      while (__hip_atomic_load(&flags[src], __ATOMIC_ACQUIRE,
                               __HIP_MEMORY_SCOPE_AGENT) == 0) {
        __builtin_amdgcn_s_sleep(1);
      }
    }
  }
  __syncthreads();
  // lookback stage 1: slot=4i+jj: lkb[slot] = M^(2048*jj)*agg[b-1-slot]
#pragma unroll
  for (int r = 0; r < 2; ++r) {
    int idx = k + r*BLK;             // covers 384 = 32*12
    if (idx < 384) {
      int slot = idx / 12, comp = idx - slot*12;
      int src = b - 1 - slot;
      float acc = 0.f;
      if (src >= 0) {
        int jj = slot & 3;
        const float* ag = agg + src*12;
        acc = (jj == 0) ? ag[comp]
            : rowdot(cons + OFF_PL + (jj-1)*144 + comp*12, ag);
      }
      lkb[idx] = acc;
    }
  }
  __syncthreads();
  // yv[i] = sum_jj lkb[4i+jj]  (k<96)  |  Pw: P0=0, P1=T0  (k in [192,216))
  if (k < 96) {
    int i = k/12, comp = k - i*12;
    yv[k] = lkb[(4*i)*12+comp] + lkb[(4*i+1)*12+comp]
          + lkb[(4*i+2)*12+comp] + lkb[(4*i+3)*12+comp];
  } else if (k >= 192 && k < 216) {
    int q = k - 192;                 // 0..23
    if (q < 12) Pw[q] = 0.f;         // P0
    else Pw[q] = Tw[q-12];           // P1 = T0
  }
  __syncthreads();
  // zv[i] = M^(8192i)*yv[i] (k<96) | P2 = M^512*P1 + T1 (k in [192,204))
  if (k < 96) {
    int i = k/12, comp = k - i*12;
    zv[k] = (i == 0) ? yv[comp]
          : rowdot(cons + OFF_PD + i*144 + comp*12, yv + i*12);
  } else if (k >= 192 && k < 204) {
    int comp = k - 192;
    Pw[24+comp] = rowdot(cons + OFF_P2 + 6*144 + comp*12, Pw+12) + Tw[12+comp];
  }
  __syncthreads();
  // Xs = sum_i zv[i] (k<12) | P3 = M^512*P2 + T2 (k in [192,204))
  if (k < 12) {
    float s = 0.f;
#pragma unroll
    for (int i = 0; i < 8; ++i) s += zv[i*12 + k];
    Xs[k] = s;
  } else if (k >= 192 && k < 204) {
    int comp = k - 192;
    Pw[36+comp] = rowdot(cons + OFF_P2 + 6*144 + comp*12, Pw+24) + Tw[24+comp];
  }
  __syncthreads();
  // Qw[w] = M^(512w)*Xs + Pw[w]  (w=0..3; matrices I, M^512, M^1024, M^1536)
  if (k < 48) {
    int ww = k/12, comp = k - ww*12;
    float acc;
    if (ww == 0) acc = Xs[comp];
    else if (ww == 1) acc = rowdot(cons + OFF_P2 + 6*144 + comp*12, Xs);
    else if (ww == 2) acc = rowdot(cons + OFF_P2 + 7*144 + comp*12, Xs);
    else acc = rowdot(cons + OFF_PA + comp*12, Xs);
    Qw[k] = acc + Pw[k];
  }
  __syncthreads();
  if (!active) return;               // all barriers done
  // per-thread: x = M^(8j)*Qw[w] + se   (bits of j, P2[0..5])
  float x[12];
#pragma unroll
  for (int i = 0; i < 12; ++i) x[i] = Qw[w*12 + i];
#pragma unroll
  for (int l = 0; l < 6; ++l) {
    if ((j >> l) & 1) {
      float vn[12];
#pragma unroll
      for (int i = 0; i < 12; ++i) vn[i] = 0.f;
      mv_acc(cons + OFF_P2 + l*144, x, vn);
#pragma unroll
      for (int i = 0; i < 12; ++i) x[i] = vn[i];
    }
  }
#pragma unroll
  for (int i = 0; i < 12; ++i) x[i] += se[i];
  if (b == 0 && k == 0) {
#pragma unroll
    for (int i = 0; i < 12; ++i) x[i] += x0[i];      // start state = x0
#pragma unroll
    for (int i = 0; i < 12; ++i) out[i] = x0[i];     // row 0
  }
  // expand: 8 unconditional steps, predicated stores (NO break)
  float cv[12], av[12], bv[12];
#pragma unroll
  for (int i = 0; i < 12; ++i) {
    cv[i] = cons[OFF_C + i]; av[i] = cons[OFF_AL + i]; bv[i] = cons[OFF_BE + i];
  }
  const float4* Mq = reinterpret_cast<const float4*>(cons + OFF_M);
#pragma unroll
  for (int s = 0; s < CH; ++s) {
    float tot = to_[s], ton = to_[s+1];
    float xn[12];
#pragma unroll
    for (int i = 0; i < 12; ++i) {
      float4 a = Mq[3*i], bq = Mq[3*i+1], c = Mq[3*i+2];
      xn[i] = FMA4(c, x[8],x[9],x[10],x[11],
               FMA4(bq, x[4],x[5],x[6],x[7],
                FMA4(a, x[0],x[1],x[2],x[3],
                 fmaf(bv[i],ton,fmaf(av[i],tot,cv[i])))));
    }
    int tt = base + s;
    if (tt < S_STEPS) {
      float4* op = reinterpret_cast<float4*>(out + (size_t)(tt+1)*12);
      op[0] = make_float4(xn[0],xn[1],xn[2],xn[3]);
      op[1] = make_float4(xn[4],xn[5],xn[6],xn[7]);
      op[2] = make_float4(xn[8],xn[9],xn[10],xn[11]);
    }
#pragma unroll
    for (int i = 0; i < 12; ++i) x[i] = xn[i];
  }
}

extern "C" void kernel_launch(void* const* d_in, const int* in_sizes, int n_in,
                              void* d_out, int out_size, void* d_ws, size_t ws_size,
                              hipStream_t stream) {
  const float* t_eval    = (const float*)d_in[0];
  const float* x0        = (const float*)d_in[1];
  const float* A         = (const float*)d_in[2];
  const float* B         = (const float*)d_in[3];
  const float* To        = (const float*)d_in[4];
  const float* loads_raw = (const float*)d_in[5];
  const float* areas     = (const float*)d_in[6];
  float* out = (float*)d_out;
  float* ws  = (float*)d_ws;

  setup_kernel<<<1, 512, 0, stream>>>(t_eval, A, B, loads_raw, areas, ws);
  fused_scan<<<NB, BLK, 0, stream>>>(ws, To, x0, ws + OFF_AGG,
                                     (int*)(ws + OFF_FLAG), out);
}

// Round 7
// 130.940 us; speedup vs baseline: 1.5618x; 1.0346x over previous
//
#include <hip/hip_runtime.h>
#include <math.h>

// RC thermal model: x' = A x + b0*To(t) + Bq, RK4 h=30, T=1e6 steps.
// Per step: x_{t+1} = M x_t + c + al*To[t] + be*To[t+1].
// R14: fused kernel (R13 structure: publish/spin lookback, plain launch)
// + LDS-mirrored constants. R13 showed fused=55.5us at 13.5% VALU, 17%
// occ: ~85% stall. Theory: matrix reads (M/K/P2/PD/PL) share the vmcnt
// queue with To loads AND out stores (stores count in vmcnt on CDNA);
// waiting on a matrix load forces draining older HBM stores (~500-900cy)
// -- every expand step and scan level pays it. R12 lesson: register
// preload = scratch demotion; the CDNA-robust fix is LDS: block start
// copies cons[0..3200) (12.8KB, 800 float4, coalesced, overlapped with
// To loads) into LDS; all matvecs become ds_read_b128 (lgkmcnt --
// decoupled from vmcnt; uniform-address = broadcast, conflict-free).
// R15: resubmit of R14 unchanged -- R14 bench was an infra failure
// ("container failed twice"); audit found no deadlock path (co-residency
// 489 <= 512 at 15.5KB LDS / 2 blocks/CU; R13 passed identical sync).
// Structure: setup (plain) + fused_scan (plain). CH=8, BLK=256, NB=489.

#define S_STEPS 999999
#define CH      8
#define BLK     256
#define NB      489          // 489*256*8 = 1,001,472 >= S_STEPS
#define NCHUNK  125000       // active chunks (last partial: 7 steps)
#define LASTFULL 124998      // g <= LASTFULL: To[8g+8] in bounds

// ws float offsets (16B-aligned)
#define OFF_M   0            // 144: M
#define OFF_C   144          // 12
#define OFF_AL  156          // 12
#define OFF_BE  168          // 12
#define OFF_K   192          // 120: K cols [col][12], col0 = const (10 cols)
#define OFF_P2  320          // 8*144: [l]=M^(8*2^l) l=0..5 (M^8..M^256),
                             //        [6]=M^512, [7]=M^1024
#define OFF_PA  1472         // 144: M^1536
#define OFF_PL  1616         // 3*144: M^2048, M^4096, M^6144
#define OFF_PD  2048         // 8*144: Pd[i]=M^(8192*i), i=0..7 (Pd[0]=I)
#define NCONS   3200         // floats mirrored to LDS (= OFF_PD+1152)
#define OFF_AGG 3200         // 489*12 block aggregates (end 9068)
#define OFF_FLAG 9072        // 489 int flags (16B-aligned)

#define FMA4(Q,a,b,c,d,acc) fmaf((Q).w,(d),fmaf((Q).z,(c),fmaf((Q).y,(b),fmaf((Q).x,(a),(acc)))))

// y += P(12x12 row-major, 16B-aligned) * x
__device__ __forceinline__ void mv_acc(const float* Pf, const float* x, float* y) {
  const float4* P = reinterpret_cast<const float4*>(Pf);
#pragma unroll
  for (int i = 0; i < 12; ++i) {
    float4 a = P[3*i], b = P[3*i+1], c = P[3*i+2];
    y[i] = FMA4(c, x[8],x[9],x[10],x[11],
            FMA4(b, x[4],x[5],x[6],x[7],
             FMA4(a, x[0],x[1],x[2],x[3], y[i])));
  }
}

// dot(P row (16B-aligned), xv[0..11] scalars)
__device__ __forceinline__ float rowdot(const float* Prow, const float* xv) {
  const float4* P = reinterpret_cast<const float4*>(Prow);
  float4 a = P[0], b = P[1], c = P[2];
  return FMA4(c, xv[8],xv[9],xv[10],xv[11],
          FMA4(b, xv[4],xv[5],xv[6],xv[7],
           FMA4(a, xv[0],xv[1],xv[2],xv[3], 0.f)));
}

// v = K[:,0] + sum_{s=0..8} K[:,s+1]*tos[s]
__device__ __forceinline__ void fold_chunk(const float* cons,
                                           const float* tos, float* v) {
  const float4* Kq = reinterpret_cast<const float4*>(cons + OFF_K);
  float4 c0=Kq[0], c1=Kq[1], c2=Kq[2];
  v[0]=c0.x; v[1]=c0.y; v[2]=c0.z; v[3]=c0.w;
  v[4]=c1.x; v[5]=c1.y; v[6]=c1.z; v[7]=c1.w;
  v[8]=c2.x; v[9]=c2.y; v[10]=c2.z; v[11]=c2.w;
#pragma unroll
  for (int s = 0; s < 9; ++s) {
    float ts = tos[s];
    float4 ka=Kq[3*(s+1)], kb=Kq[3*(s+1)+1], kc=Kq[3*(s+1)+2];
    v[0]=fmaf(ka.x,ts,v[0]); v[1]=fmaf(ka.y,ts,v[1]); v[2]=fmaf(ka.z,ts,v[2]); v[3]=fmaf(ka.w,ts,v[3]);
    v[4]=fmaf(kb.x,ts,v[4]); v[5]=fmaf(kb.y,ts,v[5]); v[6]=fmaf(kb.z,ts,v[6]); v[7]=fmaf(kb.w,ts,v[7]);
    v[8]=fmaf(kc.x,ts,v[8]); v[9]=fmaf(kc.y,ts,v[9]); v[10]=fmaf(kc.z,ts,v[10]); v[11]=fmaf(kc.w,ts,v[11]);
  }
}

__global__ void __launch_bounds__(512) setup_kernel(
    const float* __restrict__ t_eval, const float* __restrict__ A,
    const float* __restrict__ Bm, const float* __restrict__ loads_raw,
    const float* __restrict__ areas, float* ws) {
  __shared__ double H1[144], H2[144], H3[144], H4[144], Md[144];
  __shared__ double Qa[144], Qb[144];
  __shared__ double C512s[144], C1024s[144], C2048s[144], C4096s[144];
  __shared__ double C8192s[144], C16384s[144], C32768s[144], Pd3s[144];
  __shared__ double cd[12], ald[12], bed[12], b0d[12], bqd[12];
  __shared__ double Vv[3][12], Kd[120];
  int t = threadIdx.x;
  if (t < NB) ((int*)(ws + OFF_FLAG))[t] = 0;   // reset lookback flags
  double h = (double)t_eval[1] - (double)t_eval[0];
  if (t < 144) H1[t] = h * (double)A[t];
  if (t < 12) {
    b0d[t] = (double)Bm[t*11];
    double s = 0.0;
    for (int r = 0; r < 10; ++r) {
      double gq = 50.0 / (1.0 + exp(-(double)loads_raw[10 + r]));
      s += (double)Bm[t*11 + 1 + r] * (gq * (double)areas[r]);
    }
    bqd[t] = s;
  }
  if (t < 120) Kd[t] = 0.0;
  __syncthreads();
  if (t < 144) {                              // H2 = H1*H1
    int i=t/12, j=t%12; double s=0.0;
#pragma unroll
    for (int m = 0; m < 12; ++m) s += H1[i*12+m]*H1[m*12+j];
    H2[t]=s;
  }
  __syncthreads();
  if (t < 288) {                              // H3 = H2*H1 | H4 = H2*H2
    int w=t/144, e=t%144, i=e/12, j=e%12;
    const double* Bp = w ? H2 : H1;
    double s = 0.0;
#pragma unroll
    for (int m = 0; m < 12; ++m) s += H2[i*12+m]*Bp[m*12+j];
    (w ? H4 : H3)[e] = s;
  }
  __syncthreads();
  if (t < 12) {
    double hb=0,h2b=0,h3b=0,hb0=0,h2b0=0,h3b0=0;
#pragma unroll
    for (int m = 0; m < 12; ++m) {
      hb  += H1[t*12+m]*bqd[m]; h2b  += H2[t*12+m]*bqd[m]; h3b  += H3[t*12+m]*bqd[m];
      hb0 += H1[t*12+m]*b0d[m]; h2b0 += H2[t*12+m]*b0d[m]; h3b0 += H3[t*12+m]*b0d[m];
    }
    double h6 = h / 6.0;
    cd[t]  = h6*(6.0*bqd[t] + 3.0*hb + h2b + 0.25*h3b);
    ald[t] = h6*(3.0*b0d[t] + 2.0*hb0 + 0.75*h2b0 + 0.25*h3b0);
    bed[t] = h6*(3.0*b0d[t] + hb0 + 0.25*h2b0);
    Vv[0][t]=ald[t]; Vv[1][t]=bed[t]; Vv[2][t]=cd[t];
    // r=0 K contributions (CH=8): col8 += al, col9 += be, col0 += c
    Kd[96+t] += ald[t]; Kd[108+t] += bed[t]; Kd[t] += cd[t];
  }
  if (t >= 144 && t < 288) {
    int e=t-144, i=e/12, j=e%12;
    Md[e] = (i==j ? 1.0 : 0.0) + H1[e] + 0.5*H2[e] + H3[e]/6.0 + H4[e]/24.0;
  }
  __syncthreads();
  if (t < 144) { ws[OFF_M+t] = (float)Md[t]; Qa[t] = Md[t]; }
  if (t < 12) {
    ws[OFF_C+t]=(float)cd[t]; ws[OFF_AL+t]=(float)ald[t]; ws[OFF_BE+t]=(float)bed[t];
  }
  __syncthreads();
  // chain r=1..15: src=M^(2^(r-1)) -> dst=M^(2^r). Overlapped K rounds
  // r=1..7 (threads 256..291): Vv=M^r*{al,be,c}; Kd cols (8-r),(9-r),0.
  double* src = Qa; double* dst = Qb;
  for (int r = 1; r <= 15; ++r) {
    double acc = 0.0, ks = 0.0;
    if (t < 144) {
      int i=t/12, j=t%12;
#pragma unroll
      for (int m = 0; m < 12; ++m) acc += src[i*12+m]*src[m*12+j];
    }
    int w=0, i2=0;
    if (r <= 7 && t >= 256 && t < 292) {
      w=(t-256)/12; i2=(t-256)%12;
#pragma unroll
      for (int m = 0; m < 12; ++m) ks += Md[i2*12+m]*Vv[w][m];
    }
    __syncthreads();
    if (t < 144) {
      dst[t] = acc;
      if (r >= 3 && r <= 10) ws[OFF_P2+(r-3)*144+t] = (float)acc;  // M^8..M^1024
      if (r == 9)  C512s[t]=acc;
      if (r == 10) C1024s[t]=acc;
      if (r == 11) { C2048s[t]=acc;  ws[OFF_PL+t]       = (float)acc; }
      if (r == 12) { C4096s[t]=acc;  ws[OFF_PL+144+t]   = (float)acc; }
      if (r == 13) { C8192s[t]=acc;  ws[OFF_PD+144+t]   = (float)acc; }  // Pd[1]
      if (r == 14) { C16384s[t]=acc; ws[OFF_PD+2*144+t] = (float)acc; }  // Pd[2]
      if (r == 15) { C32768s[t]=acc; ws[OFF_PD+4*144+t] = (float)acc; }  // Pd[4]
    }
    if (r <= 7 && t >= 256 && t < 292) {
      Vv[w][i2] = ks;
      if (w == 0) Kd[(8-r)*12+i2] += ks;
      else if (w == 1) Kd[(9-r)*12+i2] += ks;
      else Kd[i2] += ks;
    }
    __syncthreads();
    double* tmp = src; src = dst; dst = tmp;    // src = M^(2^r)
  }
  if (t < 120) ws[OFF_K+t] = (float)Kd[t];
  if (t < 144) ws[OFF_PD+t] = (t % 13 == 0) ? 1.f : 0.f;   // Pd[0]=I
  // product round A: M^1536=M^512*M^1024 ; M^6144=M^2048*M^4096 ;
  //                  Pd[3]=M^8192*M^16384
  if (t < 432) {
    int w=t/144, e=t%144, i=e/12, j=e%12;
    const double* Ap = (w==0) ? C512s  : ((w==1) ? C2048s : C8192s);
    const double* Bp = (w==0) ? C1024s : ((w==1) ? C4096s : C16384s);
    double s = 0.0;
#pragma unroll
    for (int m = 0; m < 12; ++m) s += Ap[i*12+m]*Bp[m*12+j];
    if (w==0) ws[OFF_PA+e] = (float)s;
    else if (w==1) ws[OFF_PL+2*144+e] = (float)s;
    else { ws[OFF_PD+3*144+e] = (float)s; Pd3s[e] = s; }
  }
  __syncthreads();
  // product round B: Pd[5]=Pd[1]*M^32768 ; Pd[6]=Pd[2]*M^32768 ;
  //                  Pd[7]=Pd[3]*M^32768
  if (t < 432) {
    int w=t/144, e=t%144, i=e/12, j=e%12;
    const double* Ap = (w==0) ? C8192s : ((w==1) ? C16384s : Pd3s);
    double s = 0.0;
#pragma unroll
    for (int m = 0; m < 12; ++m) s += Ap[i*12+m]*C32768s[m*12+j];
    ws[OFF_PD+(5+w)*144+e] = (float)s;
  }
}

// Fused: LDS-mirror cons; fold+scan ONCE; publish agg[b] (release flag);
// spin on 32 predecessor flags (acquire); truncated lookback + merged
// prefix + 8-step expand. Plain launch, graph-capturable.
__global__ void __launch_bounds__(BLK, 2) fused_scan(
    const float* __restrict__ cons, const float* __restrict__ To,
    const float* __restrict__ x0, float* __restrict__ agg,
    int* __restrict__ flags, float* __restrict__ out) {
  __shared__ __align__(16) float Lc[NCONS];   // LDS mirror of cons[0..3200)
  __shared__ __align__(16) float Tw[48];      // wave totals
  __shared__ __align__(16) float Ta[24];      // agg tree level 1
  __shared__ __align__(16) float Pw[48];      // wave exclusive prefixes
  __shared__ __align__(16) float lkb[32*12];  // lookback stage-1 partials
  __shared__ __align__(16) float yv[8*12];
  __shared__ __align__(16) float zv[8*12];
  __shared__ __align__(16) float Xs[12];
  __shared__ __align__(16) float Qw[48];      // M^(512w)*Xs + Pw
  int k = threadIdx.x, b = blockIdx.x;
  int g = b*BLK + k, base = g*CH;
  bool active = (g < NCHUNK), fullc = (g <= LASTFULL);
  float to_[9];
#pragma unroll
  for (int i = 0; i < 9; ++i) to_[i] = 0.f;
  if (active) {
    const float4* tp = reinterpret_cast<const float4*>(To + base);
    float4 ta = tp[0], tb = tp[1];
    to_[0]=ta.x; to_[1]=ta.y; to_[2]=ta.z; to_[3]=ta.w;
    to_[4]=tb.x; to_[5]=tb.y; to_[6]=tb.z; to_[7]=tb.w;
    to_[8] = fullc ? To[base+8] : 0.f;
  }
  {                                  // mirror cons -> LDS (800 float4)
    const float4* s4 = reinterpret_cast<const float4*>(cons);
    float4* d4 = reinterpret_cast<float4*>(Lc);
#pragma unroll
    for (int r = 0; r < 4; ++r) {
      int idx = k + r*BLK;
      if (idx < NCONS/4) d4[idx] = s4[idx];
    }
  }
  __syncthreads();
  const float* lc = Lc;              // all constant reads now LDS
  float v[12];
  if (fullc) fold_chunk(lc, to_, v);
  else {
#pragma unroll
    for (int i = 0; i < 12; ++i) v[i] = 0.f;
  }
  if (g == 0) {                      // fold x0 into chunk 0: v += M^8 x0
    float xi[12];
#pragma unroll
    for (int i = 0; i < 12; ++i) xi[i] = x0[i];
    mv_acc(lc + OFF_P2, xi, v);
  }
  int j = k & 63, w = k >> 6;
#pragma unroll
  for (int l = 0; l < 6; ++l) {      // in-wave inclusive scan
    int off = 1 << l;
    float nb[12];
#pragma unroll
    for (int i = 0; i < 12; ++i) nb[i] = __shfl_up(v[i], (unsigned)off, 64);
    if (j >= off) mv_acc(lc + OFF_P2 + l*144, nb, v);
  }
  float se[12];                      // exclusive in-wave scan
#pragma unroll
  for (int i = 0; i < 12; ++i) {
    float u = __shfl_up(v[i], 1u, 64);
    se[i] = (j == 0) ? 0.f : u;
  }
  if (j == 63) {
#pragma unroll
    for (int i = 0; i < 12; ++i) Tw[w*12 + i] = v[i];
  }
  __syncthreads();
  if (k < 24) {                      // (T0,T1),(T2,T3): M^512*left + right
    int p = k/12, comp = k - p*12;
    Ta[k] = rowdot(lc + OFF_P2 + 6*144 + comp*12, Tw + 2*p*12)
          + Tw[(2*p+1)*12 + comp];
  }
  __syncthreads();
  if (k < 12) {                      // agg[b] = M^1024*Ta0 + Ta1 (agent)
    float val = rowdot(lc + OFF_P2 + 7*144 + k*12, Ta) + Ta[12 + k];
    __hip_atomic_store(&agg[b*12 + k], val, __ATOMIC_RELAXED,
                       __HIP_MEMORY_SCOPE_AGENT);
  }
  __syncthreads();
  if (k == 0)                        // publish: release flag
    __hip_atomic_store(&flags[b], 1, __ATOMIC_RELEASE,
                       __HIP_MEMORY_SCOPE_AGENT);
  // spin on 32 predecessors (threads k<32, one flag each)
  if (k < 32) {
    int src = b - 1 - k;
    if (src >= 0) {
      while (__hip_atomic_load(&flags[src], __ATOMIC_ACQUIRE,
                               __HIP_MEMORY_SCOPE_AGENT) == 0) {
        __builtin_amdgcn_s_sleep(1);
      }
    }
  }
  __syncthreads();
  // lookback stage 1: slot=4i+jj: lkb[slot] = M^(2048*jj)*agg[b-1-slot]
#pragma unroll
  for (int r = 0; r < 2; ++r) {
    int idx = k + r*BLK;             // covers 384 = 32*12
    if (idx < 384) {
      int slot = idx / 12, comp = idx - slot*12;
      int src = b - 1 - slot;
      float acc = 0.f;
      if (src >= 0) {
        int jj = slot & 3;
        const float* ag = agg + src*12;
        acc = (jj == 0) ? ag[comp]
            : rowdot(lc + OFF_PL + (jj-1)*144 + comp*12, ag);
      }
      lkb[idx] = acc;
    }
  }
  __syncthreads();
  // yv[i] = sum_jj lkb[4i+jj]  (k<96)  |  Pw: P0=0, P1=T0  (k in [192,216))
  if (k < 96) {
    int i = k/12, comp = k - i*12;
    yv[k] = lkb[(4*i)*12+comp] + lkb[(4*i+1)*12+comp]
          + lkb[(4*i+2)*12+comp] + lkb[(4*i+3)*12+comp];
  } else if (k >= 192 && k < 216) {
    int q = k - 192;                 // 0..23
    if (q < 12) Pw[q] = 0.f;         // P0
    else Pw[q] = Tw[q-12];           // P1 = T0
  }
  __syncthreads();
  // zv[i] = M^(8192i)*yv[i] (k<96) | P2 = M^512*P1 + T1 (k in [192,204))
  if (k < 96) {
    int i = k/12, comp = k - i*12;
    zv[k] = (i == 0) ? yv[comp]
          : rowdot(lc + OFF_PD + i*144 + comp*12, yv + i*12);
  } else if (k >= 192 && k < 204) {
    int comp = k - 192;
    Pw[24+comp] = rowdot(lc + OFF_P2 + 6*144 + comp*12, Pw+12) + Tw[12+comp];
  }
  __syncthreads();
  // Xs = sum_i zv[i] (k<12) | P3 = M^512*P2 + T2 (k in [192,204))
  if (k < 12) {
    float s = 0.f;
#pragma unroll
    for (int i = 0; i < 8; ++i) s += zv[i*12 + k];
    Xs[k] = s;
  } else if (k >= 192 && k < 204) {
    int comp = k - 192;
    Pw[36+comp] = rowdot(lc + OFF_P2 + 6*144 + comp*12, Pw+24) + Tw[24+comp];
  }
  __syncthreads();
  // Qw[w] = M^(512w)*Xs + Pw[w]  (w=0..3; matrices I, M^512, M^1024, M^1536)
  if (k < 48) {
    int ww = k/12, comp = k - ww*12;
    float acc;
    if (ww == 0) acc = Xs[comp];
    else if (ww == 1) acc = rowdot(lc + OFF_P2 + 6*144 + comp*12, Xs);
    else if (ww == 2) acc = rowdot(lc + OFF_P2 + 7*144 + comp*12, Xs);
    else acc = rowdot(lc + OFF_PA + comp*12, Xs);
    Qw[k] = acc + Pw[k];
  }
  __syncthreads();
  if (!active) return;               // all barriers done
  // per-thread: x = M^(8j)*Qw[w] + se   (bits of j, P2[0..5])
  float x[12];
#pragma unroll
  for (int i = 0; i < 12; ++i) x[i] = Qw[w*12 + i];
#pragma unroll
  for (int l = 0; l < 6; ++l) {
    if ((j >> l) & 1) {
      float vn[12];
#pragma unroll
      for (int i = 0; i < 12; ++i) vn[i] = 0.f;
      mv_acc(lc + OFF_P2 + l*144, x, vn);
#pragma unroll
      for (int i = 0; i < 12; ++i) x[i] = vn[i];
    }
  }
#pragma unroll
  for (int i = 0; i < 12; ++i) x[i] += se[i];
  if (b == 0 && k == 0) {
#pragma unroll
    for (int i = 0; i < 12; ++i) x[i] += x0[i];      // start state = x0
#pragma unroll
    for (int i = 0; i < 12; ++i) out[i] = x0[i];     // row 0
  }
  // expand: 8 unconditional steps, predicated stores (NO break).
  // M, c, al, be read from LDS (lgkmcnt) -- decoupled from store vmcnt.
  float cv[12], av[12], bv[12];
#pragma unroll
  for (int i = 0; i < 12; ++i) {
    cv[i] = lc[OFF_C + i]; av[i] = lc[OFF_AL + i]; bv[i] = lc[OFF_BE + i];
  }
  const float4* Mq = reinterpret_cast<const float4*>(lc + OFF_M);
#pragma unroll
  for (int s = 0; s < CH; ++s) {
    float tot = to_[s], ton = to_[s+1];
    float xn[12];
#pragma unroll
    for (int i = 0; i < 12; ++i) {
      float4 a = Mq[3*i], bq = Mq[3*i+1], c = Mq[3*i+2];
      xn[i] = FMA4(c, x[8],x[9],x[10],x[11],
               FMA4(bq, x[4],x[5],x[6],x[7],
                FMA4(a, x[0],x[1],x[2],x[3],
                 fmaf(bv[i],ton,fmaf(av[i],tot,cv[i])))));
    }
    int tt = base + s;
    if (tt < S_STEPS) {
      float4* op = reinterpret_cast<float4*>(out + (size_t)(tt+1)*12);
      op[0] = make_float4(xn[0],xn[1],xn[2],xn[3]);
      op[1] = make_float4(xn[4],xn[5],xn[6],xn[7]);
      op[2] = make_float4(xn[8],xn[9],xn[10],xn[11]);
    }
#pragma unroll
    for (int i = 0; i < 12; ++i) x[i] = xn[i];
  }
}

extern "C" void kernel_launch(void* const* d_in, const int* in_sizes, int n_in,
                              void* d_out, int out_size, void* d_ws, size_t ws_size,
                              hipStream_t stream) {
  const float* t_eval    = (const float*)d_in[0];
  const float* x0        = (const float*)d_in[1];
  const float* A         = (const float*)d_in[2];
  const float* B         = (const float*)d_in[3];
  const float* To        = (const float*)d_in[4];
  const float* loads_raw = (const float*)d_in[5];
  const float* areas     = (const float*)d_in[6];
  float* out = (float*)d_out;
  float* ws  = (float*)d_ws;

  setup_kernel<<<1, 512, 0, stream>>>(t_eval, A, B, loads_raw, areas, ws);
  fused_scan<<<NB, BLK, 0, stream>>>(ws, To, x0, ws + OFF_AGG,
                                     (int*)(ws + OFF_FLAG), out);
}